// Round 1
// baseline (366.658 us; speedup 1.0000x reference)
//
#include <hip/hip_runtime.h>
#include <hip/hip_bf16.h>

#define B_ 128
#define T_ 512
#define H_ 128
#define V_ 64
#define G4_ 512  // 4*H

typedef _Float16 h2_t __attribute__((ext_vector_type(2)));
typedef _Float16 h8_t __attribute__((ext_vector_type(8)));

__device__ __forceinline__ float dot2f(h2_t a, h2_t b, float c) {
#if __has_builtin(__builtin_amdgcn_fdot2)
  return __builtin_amdgcn_fdot2(a, b, c, false);
#else
  return fmaf((float)a[1], (float)b[1], fmaf((float)a[0], (float)b[0], c));
#endif
}

__device__ __forceinline__ float ex2(float x) {
#if __has_builtin(__builtin_amdgcn_exp2f)
  return __builtin_amdgcn_exp2f(x);
#else
  return exp2f(x);
#endif
}

__device__ __forceinline__ float rcpf_(float x) {
#if __has_builtin(__builtin_amdgcn_rcpf)
  return __builtin_amdgcn_rcpf(x);
#else
  return 1.0f / x;
#endif
}

// sigmoid(x) = 1/(1+2^(-x*log2e))
__device__ __forceinline__ float sigm(float x) {
  return rcpf_(1.0f + ex2(-1.4426950408889634f * x));
}
// tanh(x) = (2^(2x*log2e)-1)/(2^(2x*log2e)+1); args here are O(1), no overflow risk
__device__ __forceinline__ float tanh_(float x) {
  float e = ex2(2.8853900817779268f * x);
  return (e - 1.0f) * rcpf_(e + 1.0f);
}

// ---------------------------------------------------------------------------
// K1: P[dir][v][j] = dot(emb[v,:], w_ih[dir][j,:]) + b_ih[j] + b_hh[j]
// grid = 128 (2 dirs * 64 vocab), block = 512 (one thread per gate j)
// ---------------------------------------------------------------------------
__global__ __launch_bounds__(512) void k_tables(
    const float* __restrict__ emb,
    const float* __restrict__ w_ih_f, const float* __restrict__ b_ih_f,
    const float* __restrict__ b_hh_f,
    const float* __restrict__ w_ih_b, const float* __restrict__ b_ih_b,
    const float* __restrict__ b_hh_b,
    float* __restrict__ Ptab) {
  const int dir = blockIdx.x >> 6;
  const int v = blockIdx.x & 63;
  const int j = threadIdx.x;
  const float* w_ih = dir ? w_ih_b : w_ih_f;
  const float* bi = dir ? b_ih_b : b_ih_f;
  const float* bh = dir ? b_hh_b : b_hh_f;
  const float4* e4 = (const float4*)(emb + v * H_);
  const float4* w4 = (const float4*)(w_ih + j * H_);
  float a0 = 0.f, a1 = 0.f, a2 = 0.f, a3 = 0.f;
#pragma unroll
  for (int q = 0; q < H_ / 4; ++q) {
    float4 e = e4[q];
    float4 w = w4[q];
    a0 = fmaf(e.x, w.x, a0);
    a1 = fmaf(e.y, w.y, a1);
    a2 = fmaf(e.z, w.z, a2);
    a3 = fmaf(e.w, w.w, a3);
  }
  Ptab[dir * (V_ * G4_) + v * G4_ + j] = (a0 + a1) + (a2 + a3) + bi[j] + bh[j];
}

// ---------------------------------------------------------------------------
// K2: persistent per-(batch,dir) LSTM scan. grid = 256 = B*2, block = 512.
// Thread j owns gate j; w_hh[j,:] lives in 64 packed fp16x2 VGPRs.
// LDS: fp32 P table (128 KB) + gate exchange + fp16 h + x offsets.
// 1 block/CU by LDS capacity (intentional).
// ---------------------------------------------------------------------------
__global__ __launch_bounds__(512, 1) void k_scan(
    const int* __restrict__ x,
    const float* __restrict__ w_hh_f,
    const float* __restrict__ w_hh_b,
    const float* __restrict__ Ptab,
    _Float16* __restrict__ hs) {
  __shared__ __align__(16) float P[V_ * G4_];   // 128 KB
  __shared__ float gates[G4_];                  // 2 KB
  __shared__ __align__(16) h8_t hbuf8[H_ / 8];  // 256 B
  __shared__ int xoff[T_];                      // 2 KB

  const int tid = threadIdx.x;
  const int b = blockIdx.x >> 1;
  const int dir = blockIdx.x & 1;

  // stage P table, coalesced float4
  {
    const float4* src = (const float4*)(Ptab + dir * (V_ * G4_));
    float4* dst = (float4*)P;
#pragma unroll
    for (int i = 0; i < (V_ * G4_ / 4) / 512; ++i)
      dst[tid + i * 512] = src[tid + i * 512];
  }
  // x row -> precomputed float-offset into P
  xoff[tid] = x[(b << 9) + tid] << 9;
  if (tid < H_) ((_Float16*)hbuf8)[tid] = (_Float16)0.f;

  // load w_hh row j, convert to fp16 pairs (one-time, L2-resident)
  const float* W = (dir ? w_hh_b : w_hh_f) + tid * H_;
  h2_t w2[H_ / 2];
#pragma unroll
  for (int kk = 0; kk < H_ / 2; ++kk) {
    float2 ww = ((const float2*)W)[kk];
    w2[kk] = h2_t{(_Float16)ww.x, (_Float16)ww.y};
  }

  float c_reg = 0.f;
  const int gtype = tid >> 7;  // 0:i 1:f 2:g 3:o  (wave-uniform)
  __syncthreads();

  for (int s = 0; s < T_; ++s) {
    const int t = dir ? (T_ - 1 - s) : s;
    // gate_j = P[x_t][j] + sum_k w_hh[j,k] * h[k]
    float acc0 = P[xoff[t] + tid];
    float acc1 = 0.f, acc2 = 0.f, acc3 = 0.f;
#pragma unroll
    for (int q = 0; q < H_ / 8; ++q) {
      h8_t hv = hbuf8[q];  // broadcast ds_read_b128
      acc0 = dot2f(h2_t{hv[0], hv[1]}, w2[4 * q + 0], acc0);
      acc1 = dot2f(h2_t{hv[2], hv[3]}, w2[4 * q + 1], acc1);
      acc2 = dot2f(h2_t{hv[4], hv[5]}, w2[4 * q + 2], acc2);
      ac3:;
      acc3 = dot2f(h2_t{hv[6], hv[7]}, w2[4 * q + 3], acc3);
    }
    float gv = (acc0 + acc1) + (acc2 + acc3);
    gates[tid] = (gtype == 2) ? tanh_(gv) : sigm(gv);
    __syncthreads();
    if (tid < H_) {
      float gi = gates[tid];
      float gf = gates[H_ + tid];
      float gg = gates[2 * H_ + tid];
      float go = gates[3 * H_ + tid];
      c_reg = fmaf(gf, c_reg, gi * gg);
      float hv = go * tanh_(c_reg);
      ((_Float16*)hbuf8)[tid] = (_Float16)hv;
      hs[(((size_t)(b << 9) + t) << 8) + (dir << 7) + tid] = (_Float16)hv;
    }
    __syncthreads();
  }
}

// ---------------------------------------------------------------------------
// K3: out[row, v] = dot(hs[row, 0:256], fc_w[v, 0:256]) + fc_b[v]
// grid = 256, block = 256; thread owns one row, 64 fp32 accumulators.
// fc_w staged to LDS as fp16.
// ---------------------------------------------------------------------------
__global__ __launch_bounds__(256) void k_fc(
    const _Float16* __restrict__ hs,
    const float* __restrict__ fc_w,
    const float* __restrict__ fc_b,
    float* __restrict__ out) {
  __shared__ __align__(16) _Float16 Wl[V_ * 2 * H_];  // 32 KB
  __shared__ float bl[V_];
  const int tid = threadIdx.x;
  for (int i = tid; i < V_ * 2 * H_; i += 256) Wl[i] = (_Float16)fc_w[i];
  if (tid < V_) bl[tid] = fc_b[tid];
  __syncthreads();

  const size_t row = (size_t)blockIdx.x * 256 + tid;
  const h8_t* h8 = (const h8_t*)(hs + (row << 8));
  float acc[V_];
#pragma unroll
  for (int v = 0; v < V_; ++v) acc[v] = 0.f;

  for (int ch = 0; ch < 8; ++ch) {  // 8 chunks of 32 h-elements
    h8_t hv0 = h8[ch * 4 + 0];
    h8_t hv1 = h8[ch * 4 + 1];
    h8_t hv2 = h8[ch * 4 + 2];
    h8_t hv3 = h8[ch * 4 + 3];
#pragma unroll
    for (int v = 0; v < V_; ++v) {
      const h8_t* w8 = (const h8_t*)(Wl + v * 256 + ch * 32);
      float a = acc[v];
      h8_t wv = w8[0];
      a = dot2f(h2_t{hv0[0], hv0[1]}, h2_t{wv[0], wv[1]}, a);
      a = dot2f(h2_t{hv0[2], hv0[3]}, h2_t{wv[2], wv[3]}, a);
      a = dot2f(h2_t{hv0[4], hv0[5]}, h2_t{wv[4], wv[5]}, a);
      a = dot2f(h2_t{hv0[6], hv0[7]}, h2_t{wv[6], wv[7]}, a);
      wv = w8[1];
      a = dot2f(h2_t{hv1[0], hv1[1]}, h2_t{wv[0], wv[1]}, a);
      a = dot2f(h2_t{hv1[2], hv1[3]}, h2_t{wv[2], wv[3]}, a);
      a = dot2f(h2_t{hv1[4], hv1[5]}, h2_t{wv[4], wv[5]}, a);
      a = dot2f(h2_t{hv1[6], hv1[7]}, h2_t{wv[6], wv[7]}, a);
      wv = w8[2];
      a = dot2f(h2_t{hv2[0], hv2[1]}, h2_t{wv[0], wv[1]}, a);
      a = dot2f(h2_t{hv2[2], hv2[3]}, h2_t{wv[2], wv[3]}, a);
      a = dot2f(h2_t{hv2[4], hv2[5]}, h2_t{wv[4], wv[5]}, a);
      a = dot2f(h2_t{hv2[6], hv2[7]}, h2_t{wv[6], wv[7]}, a);
      wv = w8[3];
      a = dot2f(h2_t{hv3[0], hv3[1]}, h2_t{wv[0], wv[1]}, a);
      a = dot2f(h2_t{hv3[2], hv3[3]}, h2_t{wv[2], wv[3]}, a);
      a = dot2f(h2_t{hv3[4], hv3[5]}, h2_t{wv[4], wv[5]}, a);
      a = dot2f(h2_t{hv3[6], hv3[7]}, h2_t{wv[6], wv[7]}, a);
      acc[v] = a;
    }
  }
  float* orow = out + (row << 6);
#pragma unroll
  for (int v = 0; v < V_; v += 4) {
    float4 o = make_float4(acc[v] + bl[v], acc[v + 1] + bl[v + 1],
                           acc[v + 2] + bl[v + 2], acc[v + 3] + bl[v + 3]);
    *(float4*)(orow + v) = o;
  }
}

extern "C" void kernel_launch(void* const* d_in, const int* in_sizes, int n_in,
                              void* d_out, int out_size, void* d_ws, size_t ws_size,
                              hipStream_t stream) {
  const int* x = (const int*)d_in[0];
  const float* emb = (const float*)d_in[1];
  const float* w_ih_f = (const float*)d_in[2];
  const float* w_hh_f = (const float*)d_in[3];
  const float* b_ih_f = (const float*)d_in[4];
  const float* b_hh_f = (const float*)d_in[5];
  const float* w_ih_b = (const float*)d_in[6];
  const float* w_hh_b = (const float*)d_in[7];
  const float* b_ih_b = (const float*)d_in[8];
  const float* b_hh_b = (const float*)d_in[9];
  const float* fc_w = (const float*)d_in[10];
  const float* fc_b = (const float*)d_in[11];
  float* out = (float*)d_out;

  // workspace layout: [P tables: 2*64*512 fp32 = 256 KB][hs: B*T*256 fp16 = 32 MB]
  float* Ptab = (float*)d_ws;
  _Float16* hs = (_Float16*)((char*)d_ws + (size_t)2 * V_ * G4_ * sizeof(float));

  k_tables<<<2 * V_, G4_, 0, stream>>>(emb, w_ih_f, b_ih_f, b_hh_f, w_ih_b,
                                       b_ih_b, b_hh_b, Ptab);
  k_scan<<<B_ * 2, G4_, 0, stream>>>(x, w_hh_f, w_hh_b, Ptab, hs);
  k_fc<<<B_ * T_ / 256, 256, 0, stream>>>(hs, fc_w, fc_b, out);
}

// Round 2
// 342.828 us; speedup vs baseline: 1.0695x; 1.0695x over previous
//
#include <hip/hip_runtime.h>
#include <hip/hip_bf16.h>

#define B_ 128
#define T_ 512
#define H_ 128
#define V_ 64
#define G4_ 512  // 4*H

typedef _Float16 h2_t __attribute__((ext_vector_type(2)));
typedef _Float16 h8_t __attribute__((ext_vector_type(8)));
struct h8s { h2_t p[4]; };

__device__ __forceinline__ float dot2f(h2_t a, h2_t b, float c) {
#if __has_builtin(__builtin_amdgcn_fdot2)
  return __builtin_amdgcn_fdot2(a, b, c, false);
#else
  return fmaf((float)a[1], (float)b[1], fmaf((float)a[0], (float)b[0], c));
#endif
}

__device__ __forceinline__ float ex2(float x) {
#if __has_builtin(__builtin_amdgcn_exp2f)
  return __builtin_amdgcn_exp2f(x);
#else
  return exp2f(x);
#endif
}

__device__ __forceinline__ float rcpf_(float x) {
#if __has_builtin(__builtin_amdgcn_rcpf)
  return __builtin_amdgcn_rcpf(x);
#else
  return 1.0f / x;
#endif
}

// DPP quad-perm controls
#define QP_XOR1 0xB1  // [1,0,3,2]
#define QP_XOR2 0x4E  // [2,3,0,1]
#define QP_BC0 0x00
#define QP_BC1 0x55
#define QP_BC2 0xAA
#define QP_BC3 0xFF

template <int CTRL>
__device__ __forceinline__ float qperm(float v) {
#if __has_builtin(__builtin_amdgcn_update_dpp)
  return __builtin_bit_cast(
      float, __builtin_amdgcn_update_dpp(0, __builtin_bit_cast(int, v), CTRL,
                                         0xf, 0xf, true));
#else
  int lane = (int)(threadIdx.x & 3);
  int src;
  if constexpr (CTRL == QP_XOR1) src = lane ^ 1;
  else if constexpr (CTRL == QP_XOR2) src = lane ^ 2;
  else src = CTRL & 3;
  return __shfl(v, ((int)threadIdx.x & ~3) + src, 64);
#endif
}

// ---------------------------------------------------------------------------
// K1: P[dir][v][j] = dot(emb[v,:], w_ih[dir][j,:]) + b_ih[j] + b_hh[j]
// ---------------------------------------------------------------------------
__global__ __launch_bounds__(512) void k_tables(
    const float* __restrict__ emb,
    const float* __restrict__ w_ih_f, const float* __restrict__ b_ih_f,
    const float* __restrict__ b_hh_f,
    const float* __restrict__ w_ih_b, const float* __restrict__ b_ih_b,
    const float* __restrict__ b_hh_b,
    float* __restrict__ Ptab) {
  const int dir = blockIdx.x >> 6;
  const int v = blockIdx.x & 63;
  const int j = threadIdx.x;
  const float* w_ih = dir ? w_ih_b : w_ih_f;
  const float* bi = dir ? b_ih_b : b_ih_f;
  const float* bh = dir ? b_hh_b : b_hh_f;
  const float4* e4 = (const float4*)(emb + v * H_);
  const float4* w4 = (const float4*)(w_ih + j * H_);
  float a0 = 0.f, a1 = 0.f, a2 = 0.f, a3 = 0.f;
#pragma unroll
  for (int q = 0; q < H_ / 4; ++q) {
    float4 e = e4[q];
    float4 w = w4[q];
    a0 = fmaf(e.x, w.x, a0);
    a1 = fmaf(e.y, w.y, a1);
    a2 = fmaf(e.z, w.z, a2);
    a3 = fmaf(e.w, w.w, a3);
  }
  Ptab[dir * (V_ * G4_) + v * G4_ + j] = (a0 + a1) + (a2 + a3) + bi[j] + bh[j];
}

// ---------------------------------------------------------------------------
// K2: persistent per-(batch,dir) LSTM scan. grid = 256, block = 512.
// Lane mapping: wave w, lane l -> h-index k = w*16 + (l>>2), gate g = l&3.
// Each lane computes gate row (g*128+k) over h-quarter [g*32, g*32+32).
// Quad DPP transpose-reduce -> full gate per lane; DPP broadcast -> all 4
// gates in every lane; c replicated per quad. One barrier/step (h dbuf).
// ---------------------------------------------------------------------------
__global__ __launch_bounds__(512, 1) void k_scan(
    const int* __restrict__ x,
    const float* __restrict__ w_hh_f,
    const float* __restrict__ w_hh_b,
    const float* __restrict__ Ptab,
    _Float16* __restrict__ hs) {
  __shared__ __align__(16) float P[V_ * G4_];       // 128 KB
  __shared__ int xoff[T_];                          // 2 KB
  __shared__ __align__(16) _Float16 hb[2][H_];      // 512 B

  const int tid = threadIdx.x;
  const int b = blockIdx.x >> 1;
  const int dir = blockIdx.x & 1;
  const int l = tid & 63;
  const int w = tid >> 6;
  const int g = l & 3;
  const int k = (w << 4) + (l >> 2);

  // stage P table, coalesced float4
  {
    const float4* src = (const float4*)(Ptab + dir * (V_ * G4_));
    float4* dst = (float4*)P;
#pragma unroll
    for (int i = 0; i < (V_ * G4_ / 4) / 512; ++i)
      dst[tid + i * 512] = src[tid + i * 512];
  }
  xoff[tid] = x[(b << 9) + tid] << 9;
  if (tid < H_) hb[0][tid] = (_Float16)0.f;

  // load weight quarters: rows j*128+k, elements [g*32, g*32+32), fp16 pairs
  const float* W = dir ? w_hh_b : w_hh_f;
  h2_t wr[4][16];
#pragma unroll
  for (int j = 0; j < 4; ++j) {
    const float2* wp = (const float2*)(W + (j * H_ + k) * H_ + g * 32);
#pragma unroll
    for (int e = 0; e < 16; ++e) {
      float2 ww = wp[e];
      wr[j][e] = h2_t{(_Float16)ww.x, (_Float16)ww.y};
    }
  }

  // per-lane nonlinearity constants: sigm for g in {0,1,3}, tanh for g==2
  // y = sa * rcp(1 + exp2(nm*x)) + sb
  const float nm = (g == 2) ? -2.8853900817779268f : -1.4426950408889634f;
  const float sa = (g == 2) ? 2.f : 1.f;
  const float sb = (g == 2) ? -1.f : 0.f;

  float c0 = 0.f;  // c[k], replicated across the quad
  _Float16* hsp = hs + ((size_t)(b << 9) << 8) + (dir << 7) + k;  // +t*256

  __syncthreads();

  int cur = 0;
  for (int s = 0; s < T_; ++s) {
    const int t = dir ? (T_ - 1 - s) : s;
    // h quarter g: 4x ds_read_b128 (2-way bank alias = free)
    const h8_t* hq8 = (const h8_t*)(&hb[cur][g << 5]);
    h8s q0 = __builtin_bit_cast(h8s, hq8[0]);
    h8s q1 = __builtin_bit_cast(h8s, hq8[1]);
    h8s q2 = __builtin_bit_cast(h8s, hq8[2]);
    h8s q3 = __builtin_bit_cast(h8s, hq8[3]);
    float pv = P[xoff[t] + (g << 7) + k];

    float a0 = 0.f, a1 = 0.f, a2 = 0.f, a3 = 0.f;
#pragma unroll
    for (int e = 0; e < 4; ++e) {
      a0 = dot2f(q0.p[e], wr[0][e], a0);
      a1 = dot2f(q0.p[e], wr[1][e], a1);
      a2 = dot2f(q0.p[e], wr[2][e], a2);
      a3 = dot2f(q0.p[e], wr[3][e], a3);
    }
#pragma unroll
    for (int e = 0; e < 4; ++e) {
      a0 = dot2f(q1.p[e], wr[0][4 + e], a0);
      a1 = dot2f(q1.p[e], wr[1][4 + e], a1);
      a2 = dot2f(q1.p[e], wr[2][4 + e], a2);
      a3 = dot2f(q1.p[e], wr[3][4 + e], a3);
    }
#pragma unroll
    for (int e = 0; e < 4; ++e) {
      a0 = dot2f(q2.p[e], wr[0][8 + e], a0);
      a1 = dot2f(q2.p[e], wr[1][8 + e], a1);
      a2 = dot2f(q2.p[e], wr[2][8 + e], a2);
      a3 = dot2f(q2.p[e], wr[3][8 + e], a3);
    }
#pragma unroll
    for (int e = 0; e < 4; ++e) {
      a0 = dot2f(q3.p[e], wr[0][12 + e], a0);
      a1 = dot2f(q3.p[e], wr[1][12 + e], a1);
      a2 = dot2f(q3.p[e], wr[2][12 + e], a2);
      a3 = dot2f(q3.p[e], wr[3][12 + e], a3);
    }

    // quad transpose-reduce: lane ends with full dot for row g
    float s0 = a0 + qperm<QP_XOR1>(a0);
    float s1 = a1 + qperm<QP_XOR1>(a1);
    float s2 = a2 + qperm<QP_XOR1>(a2);
    float s3 = a3 + qperm<QP_XOR1>(a3);
    float A = (g & 1) ? s1 : s0;
    float Bv = (g & 1) ? s3 : s2;
    float A2 = A + qperm<QP_XOR2>(A);
    float B2 = Bv + qperm<QP_XOR2>(Bv);
    float gv = ((g & 2) ? B2 : A2) + pv;

    // nonlinearity (uniform code, per-lane constants)
    float e0 = ex2(nm * gv);
    float r0 = rcpf_(1.f + e0);
    float y = fmaf(sa, r0, sb);

    // broadcast all 4 gates within the quad
    float yi = qperm<QP_BC0>(y);
    float yf = qperm<QP_BC1>(y);
    float yg = qperm<QP_BC2>(y);
    float yo = qperm<QP_BC3>(y);

    c0 = fmaf(yf, c0, yi * yg);
    float ec = ex2(-2.8853900817779268f * c0);
    float rc = rcpf_(1.f + ec);
    float tc = fmaf(2.f, rc, -1.f);
    float ht = yo * tc;

    if (g == 0) {
      _Float16 hh = (_Float16)ht;
      hb[cur ^ 1][k] = hh;
      hsp[(size_t)t << 8] = hh;
    }
    __syncthreads();
    cur ^= 1;
  }
}

// ---------------------------------------------------------------------------
// K3: out[row, v] = dot(hs[row, 0:256], fc_w[v, 0:256]) + fc_b[v]
// ---------------------------------------------------------------------------
__global__ __launch_bounds__(256) void k_fc(
    const _Float16* __restrict__ hs,
    const float* __restrict__ fc_w,
    const float* __restrict__ fc_b,
    float* __restrict__ out) {
  __shared__ __align__(16) _Float16 Wl[V_ * 2 * H_];  // 32 KB
  __shared__ float bl[V_];
  const int tid = threadIdx.x;
  for (int i = tid; i < V_ * 2 * H_; i += 256) Wl[i] = (_Float16)fc_w[i];
  if (tid < V_) bl[tid] = fc_b[tid];
  __syncthreads();

  const size_t row = (size_t)blockIdx.x * 256 + tid;
  const h8_t* h8 = (const h8_t*)(hs + (row << 8));
  float acc[V_];
#pragma unroll
  for (int v = 0; v < V_; ++v) acc[v] = 0.f;

  for (int ch = 0; ch < 8; ++ch) {  // 8 chunks of 32 h-elements
    h8s hv0 = __builtin_bit_cast(h8s, h8[ch * 4 + 0]);
    h8s hv1 = __builtin_bit_cast(h8s, h8[ch * 4 + 1]);
    h8s hv2 = __builtin_bit_cast(h8s, h8[ch * 4 + 2]);
    h8s hv3 = __builtin_bit_cast(h8s, h8[ch * 4 + 3]);
#pragma unroll
    for (int v = 0; v < V_; ++v) {
      const h8_t* w8 = (const h8_t*)(Wl + v * 256 + ch * 32);
      float a = acc[v];
      h8s wv = __builtin_bit_cast(h8s, w8[0]);
      a = dot2f(hv0.p[0], wv.p[0], a);
      a = dot2f(hv0.p[1], wv.p[1], a);
      a = dot2f(hv0.p[2], wv.p[2], a);
      a = dot2f(hv0.p[3], wv.p[3], a);
      wv = __builtin_bit_cast(h8s, w8[1]);
      a = dot2f(hv1.p[0], wv.p[0], a);
      a = dot2f(hv1.p[1], wv.p[1], a);
      a = dot2f(hv1.p[2], wv.p[2], a);
      a = dot2f(hv1.p[3], wv.p[3], a);
      wv = __builtin_bit_cast(h8s, w8[2]);
      a = dot2f(hv2.p[0], wv.p[0], a);
      a = dot2f(hv2.p[1], wv.p[1], a);
      a = dot2f(hv2.p[2], wv.p[2], a);
      a = dot2f(hv2.p[3], wv.p[3], a);
      wv = __builtin_bit_cast(h8s, w8[3]);
      a = dot2f(hv3.p[0], wv.p[0], a);
      a = dot2f(hv3.p[1], wv.p[1], a);
      a = dot2f(hv3.p[2], wv.p[2], a);
      a = dot2f(hv3.p[3], wv.p[3], a);
      acc[v] = a;
    }
  }
  float* orow = out + (row << 6);
#pragma unroll
  for (int v = 0; v < V_; v += 4) {
    float4 o = make_float4(acc[v] + bl[v], acc[v + 1] + bl[v + 1],
                           acc[v + 2] + bl[v + 2], acc[v + 3] + bl[v + 3]);
    *(float4*)(orow + v) = o;
  }
}

extern "C" void kernel_launch(void* const* d_in, const int* in_sizes, int n_in,
                              void* d_out, int out_size, void* d_ws, size_t ws_size,
                              hipStream_t stream) {
  const int* x = (const int*)d_in[0];
  const float* emb = (const float*)d_in[1];
  const float* w_ih_f = (const float*)d_in[2];
  const float* w_hh_f = (const float*)d_in[3];
  const float* b_ih_f = (const float*)d_in[4];
  const float* b_hh_f = (const float*)d_in[5];
  const float* w_ih_b = (const float*)d_in[6];
  const float* w_hh_b = (const float*)d_in[7];
  const float* b_ih_b = (const float*)d_in[8];
  const float* b_hh_b = (const float*)d_in[9];
  const float* fc_w = (const float*)d_in[10];
  const float* fc_b = (const float*)d_in[11];
  float* out = (float*)d_out;

  // workspace layout: [P tables: 2*64*512 fp32 = 256 KB][hs: B*T*256 fp16 = 32 MB]
  float* Ptab = (float*)d_ws;
  _Float16* hs = (_Float16*)((char*)d_ws + (size_t)2 * V_ * G4_ * sizeof(float));

  k_tables<<<2 * V_, G4_, 0, stream>>>(emb, w_ih_f, b_ih_f, b_hh_f, w_ih_b,
                                       b_ih_b, b_hh_b, Ptab);
  k_scan<<<B_ * 2, G4_, 0, stream>>>(x, w_hh_f, w_hh_b, Ptab, hs);
  k_fc<<<B_ * T_ / 256, 256, 0, stream>>>(hs, fc_w, fc_b, out);
}